// Round 9
// baseline (1624.250 us; speedup 1.0000x reference)
//
#include <hip/hip_runtime.h>

// VoxelPooler via bucket sort.
// R5 622 | R6 600 | R7 716 REGR | R8 626 | R9 635 REGR (pool 225us) |
// R10 598 (XCD swizzle null) | R11 726 REGR | R12 629 (L3 prefetch null!) |
// R13 626 (LDS-staged pipelined gather null; pool 223us — six theories
// falsified: write granule, XCD locality, two-phase, cold reads, ILP,
// dependent-load chain. All pipes idle, bottom-up model says ~80us).
// R14 = ABLATION ROUND (m177 discipline). Production path = R10 (unchanged,
// ~598us). Appended diagnostics, repeated to clear the top-5 cutoff:
//   diag_gather  x6: production gather only (random 256-B reads + LDS
//                    atomics), asm-sink keep-alive, no global writes.
//   diag_wscatter x4: production epilogue address pattern only (64 x 400-B
//                    segments @160-KB stride per block) into a ws clone.
// Per-pass cost = dur/REP. Pre-committed matrix decides R15 (permute-split
// vs write-restructure vs biggest-term attack).
// geometry [B=4, N=6, D=41, H=16, W=44, 3] f32
// features [B, N, D, H, W, C=64] f32
// out      [B, Z*C=512, X=200, Y=200] f32

#define GRID_X 200
#define GRID_Y 200
#define GRID_Z 8
#define NCH 64
#define NB 4
#define PTS_PER_BATCH (6 * 41 * 16 * 44)   // 173184
#define TOTAL_POINTS (NB * PTS_PER_BATCH)  // 692736
#define OUT_FLOATS ((long long)NB * GRID_Z * NCH * GRID_X * GRID_Y)  // 81,920,000

#define YT 2             // y tiles per x-row
#define TILE_Y 100       // GRID_Y / YT
#define NBUCKET (NB * GRID_Z * GRID_X * YT)   // 12800
#define NXCD 8
#define LDS_STRIDE 65    // acc[y][c] padded: gather 2-way banks, epilogue ok

#define REP_G 6          // diag_gather repetitions
#define REP_W 4          // diag_wscatter repetitions

// ws layout (ints):
// cnt[NBUCKET] | starts[NBUCKET+1] | cursor[NBUCKET] | sorted[TOTAL] | pcode[TOTAL]
// | sink[NBUCKET] | clone[OUT_FLOATS] (diag only)
#define WS_CNT     0
#define WS_STARTS  (NBUCKET)
#define WS_CURSOR  (2 * NBUCKET + 1)
#define WS_SORTED  (3 * NBUCKET + 1)
#define WS_PCODE   (3 * NBUCKET + 1 + TOTAL_POINTS)
#define WS_INTS    (3 * NBUCKET + 1 + 2 * TOTAL_POINTS)
#define WS_SINK    WS_INTS
#define WS_CLONE   ((WS_SINK + NBUCKET + 3) & ~3)
#define WS_INTS_DIAG ((long long)WS_CLONE + OUT_FLOATS)

__device__ __forceinline__ bool point_voxel(const float* __restrict__ geom,
                                            const float* __restrict__ vsz,
                                            const float* __restrict__ vorg,
                                            int i, int& vx, int& vy, int& vz) {
    float px = geom[(size_t)i * 3 + 0];
    float py = geom[(size_t)i * 3 + 1];
    float pz = geom[(size_t)i * 3 + 2];
    // Exact IEEE divide + floorf to match the numpy reference at bin edges.
    vx = (int)floorf((px - vorg[0]) / vsz[0]);
    vy = (int)floorf((py - vorg[1]) / vsz[1]);
    vz = (int)floorf((pz - vorg[2]) / vsz[2]);
    return (vx >= 0 && vx < GRID_X && vy >= 0 && vy < GRID_Y &&
            vz >= 0 && vz < GRID_Z);
}

__global__ __launch_bounds__(256) void zero_cnt_kernel(int* __restrict__ cnt) {
    int i = blockIdx.x * 256 + threadIdx.x;
    if (i < NBUCKET) cnt[i] = 0;
}

// pcode: bit31=valid, bits[20:14]=yl, bits[13:0]=bucket.
__global__ __launch_bounds__(256) void hist_kernel(
    const float* __restrict__ geom, const float* __restrict__ vsz,
    const float* __restrict__ vorg, int* __restrict__ cnt,
    unsigned* __restrict__ pcode) {
    int i = blockIdx.x * 256 + threadIdx.x;
    if (i >= TOTAL_POINTS) return;
    int vx, vy, vz;
    unsigned code = 0;
    if (point_voxel(geom, vsz, vorg, i, vx, vy, vz)) {
        int b = i / PTS_PER_BATCH;
        int yt = vy / TILE_Y;
        int yl = vy - yt * TILE_Y;
        int bucket = ((b * GRID_Z + vz) * GRID_X + vx) * YT + yt;
        code = 0x80000000u | ((unsigned)yl << 14) | (unsigned)bucket;
        atomicAdd(&cnt[bucket], 1);
    }
    pcode[i] = code;
}

__global__ __launch_bounds__(256) void scan_kernel(
    const int* __restrict__ cnt, int* __restrict__ starts, int* __restrict__ cursor) {
    __shared__ int partial[256];
    int t = threadIdx.x;
    const int CHUNK = NBUCKET / 256;   // 50
    int base = t * CHUNK;
    int s = 0;
    for (int j = 0; j < CHUNK; ++j) s += cnt[base + j];
    partial[t] = s;
    __syncthreads();
    for (int off = 1; off < 256; off <<= 1) {
        int v = (t >= off) ? partial[t - off] : 0;
        __syncthreads();
        partial[t] += v;
        __syncthreads();
    }
    int run = partial[t] - s;   // exclusive prefix of this chunk
    for (int j = 0; j < CHUNK; ++j) {
        int c = cnt[base + j];
        starts[base + j] = run;
        cursor[base + j] = run;
        run += c;
    }
    if (t == 255) starts[NBUCKET] = run;
}

__global__ __launch_bounds__(256) void scatter_idx_kernel(
    const unsigned* __restrict__ pcode, int* __restrict__ cursor,
    unsigned* __restrict__ sorted) {
    int i = blockIdx.x * 256 + threadIdx.x;
    if (i >= TOTAL_POINTS) return;
    unsigned code = pcode[i];
    if (!(code & 0x80000000u)) return;
    int bucket = (int)(code & 0x3FFFu);
    unsigned yl = (code >> 14) & 0x7Fu;
    int pos = atomicAdd(&cursor[bucket], 1);
    sorted[pos] = (unsigned)i | (yl << 20);   // i < 2^20, yl < 128
}

// Production pool (R10): gather 4 pts/wave-iter, 16 lanes x float4,
// LDS acc[y][c], plain float4 epilogue, XCD-chunked swizzle.
__global__ __launch_bounds__(256) void pool_kernel(
    const float4* __restrict__ feat4, const unsigned* __restrict__ sorted,
    const int* __restrict__ starts, float4* __restrict__ out4) {
    __shared__ __align__(16) float acc[TILE_Y * LDS_STRIDE];   // 26000 B
    int t = threadIdx.x;
    int bid = (blockIdx.x % NXCD) * (NBUCKET / NXCD) + blockIdx.x / NXCD;

    float4* a4 = (float4*)acc;
    for (int i = t; i < TILE_Y * LDS_STRIDE / 4; i += 256)
        a4[i] = make_float4(0.f, 0.f, 0.f, 0.f);
    __syncthreads();

    int s0 = starts[bid];
    int s1 = starts[bid + 1];
    int w = t >> 6;            // wave 0..3
    int g = (t >> 4) & 3;      // point slot within wave
    int l = t & 15;            // float4 slot: channels 4l..4l+3

    for (int p0 = s0 + w * 4; p0 < s1; p0 += 16) {
        int p = p0 + g;
        if (p < s1) {
            unsigned pk = sorted[p];
            unsigned idx = pk & 0xFFFFFu;
            unsigned yl = pk >> 20;
            float4 f = feat4[(size_t)idx * 16 + l];
            float* row = &acc[yl * LDS_STRIDE + 4 * l];
            atomicAdd(row + 0, f.x);
            atomicAdd(row + 1, f.y);
            atomicAdd(row + 2, f.z);
            atomicAdd(row + 3, f.w);
        }
    }
    __syncthreads();

    int yt = bid & 1;
    int x = (bid >> 1) % GRID_X;
    int bz = (bid >> 1) / GRID_X;   // b*GRID_Z + z

    for (int i = t; i < NCH * (TILE_Y / 4); i += 256) {
        int cc = i / (TILE_Y / 4);
        int j = i % (TILE_Y / 4);
        int y0 = 4 * j;
        float4 v = make_float4(acc[(y0 + 0) * LDS_STRIDE + cc],
                               acc[(y0 + 1) * LDS_STRIDE + cc],
                               acc[(y0 + 2) * LDS_STRIDE + cc],
                               acc[(y0 + 3) * LDS_STRIDE + cc]);
        size_t o4 = (((size_t)bz * NCH + cc) * GRID_X + x) * (GRID_Y / 4)
                    + yt * (TILE_Y / 4) + j;
        out4[o4] = v;
    }
}

// DIAG 1: production gather only, REP_G passes. No global stores except a
// never-taken guard; asm sink on the full-acc sum keeps loads+atomics live
// (guide rule #17: ablation-via-skip DCEs upstream ops without this).
__global__ __launch_bounds__(256) void diag_gather_kernel(
    const float4* __restrict__ feat4, const unsigned* __restrict__ sorted,
    const int* __restrict__ starts, float* __restrict__ sink) {
    __shared__ __align__(16) float acc[TILE_Y * LDS_STRIDE];
    int t = threadIdx.x;
    int bid = (blockIdx.x % NXCD) * (NBUCKET / NXCD) + blockIdx.x / NXCD;

    float4* a4 = (float4*)acc;
    for (int i = t; i < TILE_Y * LDS_STRIDE / 4; i += 256)
        a4[i] = make_float4(0.f, 0.f, 0.f, 0.f);
    __syncthreads();

    int s0 = starts[bid];
    int s1 = starts[bid + 1];
    int w = t >> 6;
    int g = (t >> 4) & 3;
    int l = t & 15;

    for (int rep = 0; rep < REP_G; ++rep) {
        for (int p0 = s0 + w * 4; p0 < s1; p0 += 16) {
            int p = p0 + g;
            if (p < s1) {
                unsigned pk = sorted[p];
                unsigned idx = pk & 0xFFFFFu;
                unsigned yl = pk >> 20;
                float4 f = feat4[(size_t)idx * 16 + l];
                float* row = &acc[yl * LDS_STRIDE + 4 * l];
                atomicAdd(row + 0, f.x);
                atomicAdd(row + 1, f.y);
                atomicAdd(row + 2, f.z);
                atomicAdd(row + 3, f.w);
            }
        }
    }
    __syncthreads();

    float s = 0.f;
    for (int i = t; i < TILE_Y * LDS_STRIDE; i += 256) s += acc[i];
    asm volatile("" :: "v"(s));          // keep entire chain live
    if (s == 1.0e38f) sink[bid] = s;     // never true (inputs are ~N(0,1) sums)
}

// DIAG 2: production epilogue address pattern only, REP_W passes, into a
// ws clone region (no feature reads; LDS zeros -> same store pattern).
__global__ __launch_bounds__(256) void diag_wscatter_kernel(
    float4* __restrict__ clone4) {
    __shared__ __align__(16) float acc[TILE_Y * LDS_STRIDE];
    int t = threadIdx.x;
    int bid = (blockIdx.x % NXCD) * (NBUCKET / NXCD) + blockIdx.x / NXCD;

    float4* a4 = (float4*)acc;
    for (int i = t; i < TILE_Y * LDS_STRIDE / 4; i += 256)
        a4[i] = make_float4(0.f, 0.f, 0.f, 0.f);
    __syncthreads();

    int yt = bid & 1;
    int x = (bid >> 1) % GRID_X;
    int bz = (bid >> 1) / GRID_X;

    for (int rep = 0; rep < REP_W; ++rep) {
        for (int i = t; i < NCH * (TILE_Y / 4); i += 256) {
            int cc = i / (TILE_Y / 4);
            int j = i % (TILE_Y / 4);
            int y0 = 4 * j;
            float4 v = make_float4(acc[(y0 + 0) * LDS_STRIDE + cc],
                                   acc[(y0 + 1) * LDS_STRIDE + cc],
                                   acc[(y0 + 2) * LDS_STRIDE + cc],
                                   acc[(y0 + 3) * LDS_STRIDE + cc]);
            size_t o4 = (((size_t)bz * NCH + cc) * GRID_X + x) * (GRID_Y / 4)
                        + yt * (TILE_Y / 4) + j;
            clone4[o4] = v;
        }
    }
}

// ---------- fallback path (R4): atomic scatter ----------
__global__ __launch_bounds__(256) void zero_out_kernel(float4* __restrict__ out) {
    const long long n4 = OUT_FLOATS / 4;
    long long stride = (long long)gridDim.x * blockDim.x;
    for (long long i = blockIdx.x * (long long)blockDim.x + threadIdx.x;
         i < n4; i += stride)
        out[i] = make_float4(0.f, 0.f, 0.f, 0.f);
}

__global__ __launch_bounds__(256) void voxel_scatter_kernel(
    const float* __restrict__ geom, const float* __restrict__ feat,
    const float* __restrict__ vsz, const float* __restrict__ vorg,
    float* __restrict__ out) {
    int gid = blockIdx.x * blockDim.x + threadIdx.x;
    int pt = gid >> 6;
    int c = gid & 63;
    if (pt >= TOTAL_POINTS) return;
    int vx, vy, vz;
    if (!point_voxel(geom, vsz, vorg, pt, vx, vy, vz)) return;
    int b = pt / PTS_PER_BATCH;
    float f = feat[(size_t)pt * NCH + c];
    size_t idx = ((((size_t)b * GRID_Z + vz) * NCH + c) * GRID_X + vx) * GRID_Y + vy;
    atomicAdd(out + idx, f);
}

extern "C" void kernel_launch(void* const* d_in, const int* in_sizes, int n_in,
                              void* d_out, int out_size, void* d_ws, size_t ws_size,
                              hipStream_t stream) {
    const float* geom = (const float*)d_in[0];
    const float* feat = (const float*)d_in[1];
    const float* vsz  = (const float*)d_in[2];
    const float* vorg = (const float*)d_in[3];
    float* out = (float*)d_out;

    if (ws_size >= (size_t)WS_INTS * sizeof(int)) {
        int* ws = (int*)d_ws;
        int* cnt = ws + WS_CNT;
        int* starts = ws + WS_STARTS;
        int* cursor = ws + WS_CURSOR;
        unsigned* sorted = (unsigned*)(ws + WS_SORTED);
        unsigned* pcode  = (unsigned*)(ws + WS_PCODE);

        zero_cnt_kernel<<<(NBUCKET + 255) / 256, 256, 0, stream>>>(cnt);
        hist_kernel<<<TOTAL_POINTS / 256, 256, 0, stream>>>(geom, vsz, vorg, cnt, pcode);
        scan_kernel<<<1, 256, 0, stream>>>(cnt, starts, cursor);
        scatter_idx_kernel<<<TOTAL_POINTS / 256, 256, 0, stream>>>(pcode, cursor, sorted);
        pool_kernel<<<NBUCKET, 256, 0, stream>>>(
            (const float4*)feat, sorted, starts, (float4*)out);

        // ---- diagnostics (R14 ablation; inflate dur on purpose) ----
        if (ws_size >= (size_t)WS_INTS_DIAG * sizeof(int) + 16) {
            float* sink = (float*)(ws + WS_SINK);
            float4* clone4 = (float4*)(ws + WS_CLONE);
            diag_gather_kernel<<<NBUCKET, 256, 0, stream>>>(
                (const float4*)feat, sorted, starts, sink);
            diag_wscatter_kernel<<<NBUCKET, 256, 0, stream>>>(clone4);
        }
    } else {
        // ws too small: R4 atomic-scatter fallback
        zero_out_kernel<<<2048, 256, 0, stream>>>((float4*)out);
        const long long total_threads = (long long)TOTAL_POINTS * NCH;
        voxel_scatter_kernel<<<(int)((total_threads + 255) / 256), 256, 0, stream>>>(
            geom, feat, vsz, vorg, out);
    }
}